// Round 5
// baseline (519.219 us; speedup 1.0000x reference)
//
#include <hip/hip_runtime.h>
#include <hip/hip_fp16.h>

typedef float f32x4 __attribute__((ext_vector_type(4)));
typedef __bf16 bf16x8 __attribute__((ext_vector_type(8)));

#define CDIM 128
#define HW 256
#define NBINS 256
#define BINCAP 2560            // avg fill 1953, sigma ~44 -> +13.8 sigma headroom
#define TILES_PER_BIN 80       // BINCAP / 32
#define BINS_PER_XCD 32
#define NXCD 8

static __device__ __forceinline__ unsigned short f2bf(float f) {
    unsigned u = __builtin_bit_cast(unsigned, f);
    u += 0x7FFFu + ((u >> 16) & 1u);
    return (unsigned short)(u >> 16);
}

// ---- kernel 1: transpose plane (C,H,W) f32 -> x-major (W,H,C) f16 ----
// planeT[(x*256 + y)*128 + c]: all 8 corner rows of one point live in two
// 64-KB x-slabs -> x-bucketed points get L2-resident gathers.
__global__ __launch_bounds__(256) void k_transpose(const float* __restrict__ plane,
                                                   unsigned short* __restrict__ planeT) {
    __shared__ unsigned short tile[32][130];
    int tid = threadIdx.x;
    int y  = blockIdx.x >> 3;
    int x0 = (blockIdx.x & 7) * 32;
    int tx = tid & 31, tc = tid >> 5;
    for (int cc = 0; cc < 128; cc += 8) {
        int c = cc + tc;
        float v = plane[c * (HW * HW) + y * HW + x0 + tx];
        tile[tx][c] = __half_as_ushort(__float2half(v));
    }
    __syncthreads();
    for (int it = 0; it < 16; ++it) {
        int idx = it * 256 + tid;
        int c = idx & 127, xi = idx >> 7;
        planeT[((x0 + xi) * HW + y) * CDIM + c] = tile[xi][c];
    }
}

// ---- kernel 2: convert W1,W2 f32 -> bf16 ----
__global__ __launch_bounds__(256) void k_wconv(const float* __restrict__ W1,
                                               const float* __restrict__ W2,
                                               unsigned short* __restrict__ W1b,
                                               unsigned short* __restrict__ W2b) {
    int i = blockIdx.x * 256 + threadIdx.x;
    if (i < 16384) W1b[i] = f2bf(W1[i]);
    else           W2b[i - 16384] = f2bf(W2[i - 16384]);
}

// ---- kernel 2b: bucket points by x0 into fixed-capacity bins ----
__global__ __launch_bounds__(256) void k_scatter(const float* __restrict__ coords,
                                                 float4* __restrict__ bins,
                                                 int* __restrict__ cursor, int N) {
    int i = blockIdx.x * blockDim.x + threadIdx.x;
    int stride = gridDim.x * blockDim.x;
    for (; i < N; i += stride) {
        float gx = coords[i * 3 + 0];
        float gy = coords[i * 3 + 1];
        float gz = coords[i * 3 + 2];
        float ix = (gx + 1.f) * 127.5f;
        int b = max(0, min((int)floorf(ix), HW - 1));
        int off = atomicAdd(&cursor[b], 1);
        if (off < BINCAP) {
            float4 r; r.x = gx; r.y = gy; r.z = gz; r.w = __int_as_float(i);
            bins[b * BINCAP + off] = r;
        }
    }
}

// ---- gather helpers (x-major offsets) ----
struct PrepT {
    int off[8];     // element offsets of the 8 corner rows (incl. lane ch-group)
    float w[8];     // xy weights [0..3] = w00,w01,w10,w11; xz weights [4..7]
};

__device__ __forceinline__ PrepT prep(float gx, float gy, float gz, int cg) {
    PrepT r;
    float ix = (gx + 1.f) * 127.5f;
    float iy = (gy + 1.f) * 127.5f;
    float iz = (gz + 1.f) * 127.5f;
    float xf = floorf(ix), yf = floorf(iy), zf = floorf(iz);
    float wx1 = ix - xf, wy1 = iy - yf, wz1 = iz - zf;
    float wx0 = 1.f - wx1, wy0 = 1.f - wy1, wz0 = 1.f - wz1;
    int x0 = max(0, min((int)xf, HW - 1));
    int y0 = max(0, min((int)yf, HW - 1));
    int z0 = max(0, min((int)zf, HW - 1));
    int x1 = min(x0 + 1, HW - 1);
    int y1 = min(y0 + 1, HW - 1);
    int z1 = min(z0 + 1, HW - 1);
    int cx0 = (x0 << 15) + cg * 8, cx1 = (x1 << 15) + cg * 8;
    r.off[0] = cx0 + (y0 << 7); r.off[1] = cx1 + (y0 << 7);
    r.off[2] = cx0 + (y1 << 7); r.off[3] = cx1 + (y1 << 7);
    r.off[4] = cx0 + (z0 << 7); r.off[5] = cx1 + (z0 << 7);
    r.off[6] = cx0 + (z1 << 7); r.off[7] = cx1 + (z1 << 7);
    r.w[0] = wy0 * wx0; r.w[1] = wy0 * wx1; r.w[2] = wy1 * wx0; r.w[3] = wy1 * wx1;
    r.w[4] = wz0 * wx0; r.w[5] = wz0 * wx1; r.w[6] = wz1 * wx0; r.w[7] = wz1 * wx1;
    return r;
}

struct LdT { uint4 d[8]; };

__device__ __forceinline__ LdT ld8(const unsigned short* __restrict__ planeT, const PrepT& a) {
    LdT r;
#pragma unroll
    for (int c = 0; c < 8; ++c)
        r.d[c] = *reinterpret_cast<const uint4*>(planeT + a.off[c]);
    return r;
}

__device__ __forceinline__ void interp_store(unsigned short* dst, const PrepT& a, const LdT& L) {
    unsigned o[4];
#pragma unroll
    for (int g = 0; g < 4; ++g) {
        float2 v[8];
#pragma unroll
        for (int c = 0; c < 8; ++c) {
            unsigned wrd = reinterpret_cast<const unsigned*>(&L.d[c])[g];
            v[c] = __half22float2(__builtin_bit_cast(__half2, wrd));
        }
        float xy0 = a.w[0] * v[0].x + a.w[1] * v[1].x + a.w[2] * v[2].x + a.w[3] * v[3].x;
        float xy1 = a.w[0] * v[0].y + a.w[1] * v[1].y + a.w[2] * v[2].y + a.w[3] * v[3].y;
        float xz0 = a.w[4] * v[4].x + a.w[5] * v[5].x + a.w[6] * v[6].x + a.w[7] * v[7].x;
        float xz1 = a.w[4] * v[4].y + a.w[5] * v[5].y + a.w[6] * v[6].y + a.w[7] * v[7].y;
        float f0 = xy0 * xz0 * xz0;
        float f1 = xy1 * xz1 * xz1;
        o[g] = (unsigned)f2bf(f0) | ((unsigned)f2bf(f1) << 16);
    }
    uint4 pack; pack.x = o[0]; pack.y = o[1]; pack.z = o[2]; pack.w = o[3];
    *reinterpret_cast<uint4*>(dst) = pack;
}

// ---- kernel 3: fused sample + MLP (SORTED: bin-tiles; else direct) ----
// block = 128 threads = 2 waves; each wave owns 16 points.
// Explicit __syncthreads between LDS producer/consumer phases (R2/R3 lesson:
// mixed-type LDS access + no fence => scheduler may hoist ds_reads).
template <bool SORTED>
__global__ __launch_bounds__(128) void k_main(const float* __restrict__ coords,
                                              const float4* __restrict__ bins,
                                              const int* __restrict__ cursor,
                                              const unsigned short* __restrict__ planeT,
                                              const unsigned short* __restrict__ W1b,
                                              const unsigned short* __restrict__ W2b,
                                              const float* __restrict__ b1,
                                              const float* __restrict__ b2,
                                              const float* __restrict__ W3,
                                              const float* __restrict__ b3,
                                              float* __restrict__ out, int N) {
    __shared__ alignas(16) unsigned short feat[32][136];   // [.,128..135] = spare: orig idx
    __shared__ alignas(16) unsigned short h1s[32][136];

    const int tid  = threadIdx.x;
    const int wave = tid >> 6, lane = tid & 63;
    const int ro   = wave * 16;

    int bin = 0, base = 0, cnt = 0, pbase = 0;
    if (SORTED) {
        // block i: xcd = i&7 owns bins [xcd*32, xcd*32+32) -> contiguous 2MB
        // plane slice per XCD-L2 (assumes round-robin blockIdx->XCD; degrades
        // gracefully if mapping differs).
        int i = blockIdx.x;
        int xcd = i & 7, j = i >> 3;
        bin  = xcd * BINS_PER_XCD + j / TILES_PER_BIN;
        base = (j % TILES_PER_BIN) * 32;
        cnt  = min(cursor[bin], BINCAP);
        if (base >= cnt) return;   // uniform across block
    } else {
        pbase = blockIdx.x * 32;
    }

    // -------- phase A: bilinear sampling, 4 points/iter --------
    {
        const int pt = lane >> 4, cg = lane & 15;
#pragma unroll
        for (int it = 0; it < 4; ++it) {
            int pl = it * 4 + pt;          // local point in wave 0..15
            float gx, gy, gz; int orig;
            if (SORTED) {
                int q = min(base + ro + pl, cnt - 1);
                float4 s = bins[bin * BINCAP + q];
                gx = s.x; gy = s.y; gz = s.z; orig = __float_as_int(s.w);
            } else {
                int p = min(pbase + ro + pl, N - 1);
                gx = coords[p * 3 + 0];
                gy = coords[p * 3 + 1];
                gz = coords[p * 3 + 2];
                orig = p;
            }
            PrepT a = prep(gx, gy, gz, cg);
            LdT   d = ld8(planeT, a);
            interp_store(&feat[ro + pl][cg * 8], a, d);
            if (cg == 0) *reinterpret_cast<int*>(&feat[ro + pl][128]) = orig;
        }
    }

    __syncthreads();   // order feat ds_writes before GEMM1 ds_reads

    // -------- GEMM1: h1 = sin(30*(feat @ W1^T + b1)) --------
    const int j = lane & 15, rg = lane >> 4;
    f32x4 acc[8];
#pragma unroll
    for (int nt = 0; nt < 8; ++nt) acc[nt] = (f32x4){0.f, 0.f, 0.f, 0.f};

#pragma unroll
    for (int kk = 0; kk < 4; ++kk) {
        bf16x8 a = __builtin_bit_cast(bf16x8, *reinterpret_cast<const uint4*>(&feat[ro + j][kk * 32 + rg * 8]));
#pragma unroll
        for (int nt = 0; nt < 8; ++nt) {
            bf16x8 b = __builtin_bit_cast(bf16x8, *reinterpret_cast<const uint4*>(W1b + (nt * 16 + j) * 128 + kk * 32 + rg * 8));
            acc[nt] = __builtin_amdgcn_mfma_f32_16x16x32_bf16(a, b, acc[nt], 0, 0, 0);
        }
    }

#pragma unroll
    for (int nt = 0; nt < 8; ++nt) {
        float bb = b1[nt * 16 + j];
#pragma unroll
        for (int r = 0; r < 4; ++r) {
            float h = __sinf(30.f * (acc[nt][r] + bb));
            h1s[ro + rg * 4 + r][nt * 16 + j] = f2bf(h);
        }
    }

    __syncthreads();   // order h1s ds_writes before GEMM2 ds_reads

    // -------- GEMM2: h2 = sin(30*(h1 @ W2^T + b2)) --------
    f32x4 acc2[8];
#pragma unroll
    for (int nt = 0; nt < 8; ++nt) acc2[nt] = (f32x4){0.f, 0.f, 0.f, 0.f};

#pragma unroll
    for (int kk = 0; kk < 4; ++kk) {
        bf16x8 a = __builtin_bit_cast(bf16x8, *reinterpret_cast<const uint4*>(&h1s[ro + j][kk * 32 + rg * 8]));
#pragma unroll
        for (int nt = 0; nt < 8; ++nt) {
            bf16x8 b = __builtin_bit_cast(bf16x8, *reinterpret_cast<const uint4*>(W2b + (nt * 16 + j) * 128 + kk * 32 + rg * 8));
            acc2[nt] = __builtin_amdgcn_mfma_f32_16x16x32_bf16(a, b, acc2[nt], 0, 0, 0);
        }
    }

    // -------- epilogue: out = h2 @ W3^T + b3 --------
    float part[4] = {0.f, 0.f, 0.f, 0.f};
#pragma unroll
    for (int nt = 0; nt < 8; ++nt) {
        float bb = b2[nt * 16 + j];
        float w3 = W3[nt * 16 + j];
#pragma unroll
        for (int r = 0; r < 4; ++r)
            part[r] += __sinf(30.f * (acc2[nt][r] + bb)) * w3;
    }
#pragma unroll
    for (int off = 1; off < 16; off <<= 1) {
#pragma unroll
        for (int r = 0; r < 4; ++r) part[r] += __shfl_xor(part[r], off, 64);
    }
    if (j == 0) {
        float bb3 = b3[0];
#pragma unroll
        for (int r = 0; r < 4; ++r) {
            int pl = rg * 4 + r;
            bool live = SORTED ? (base + ro + pl < cnt) : (pbase + ro + pl < N);
            if (live) {
                int orig = *reinterpret_cast<const int*>(&feat[ro + pl][128]);
                out[orig] = part[r] + bb3;
            }
        }
    }
}

extern "C" void kernel_launch(void* const* d_in, const int* in_sizes, int n_in,
                              void* d_out, int out_size, void* d_ws, size_t ws_size,
                              hipStream_t stream) {
    const float* coords = (const float*)d_in[0];
    const float* plane  = (const float*)d_in[1];
    const float* W1     = (const float*)d_in[4];
    const float* b1     = (const float*)d_in[5];
    const float* W2     = (const float*)d_in[6];
    const float* b2     = (const float*)d_in[7];
    const float* W3     = (const float*)d_in[8];
    const float* b3     = (const float*)d_in[9];
    float* out = (float*)d_out;
    int N = in_sizes[0] / 3;

    char* ws = (char*)d_ws;
    unsigned short* planeT = (unsigned short*)ws;                         // 16 MB
    unsigned short* W1b = (unsigned short*)(ws + 16777216);               // 32 KB
    unsigned short* W2b = (unsigned short*)(ws + 16777216 + 32768);       // 32 KB
    int*    cursor = (int*)(ws + 16842752);                               // 1 KB
    float4* bins   = (float4*)(ws + 16843776);                            // 10.0 MB
    const size_t need = 16843776 + (size_t)NBINS * BINCAP * 16;

    k_transpose<<<dim3(HW * 8), dim3(256), 0, stream>>>(plane, planeT);
    k_wconv<<<dim3(128), dim3(256), 0, stream>>>(W1, W2, W1b, W2b);

    if (ws_size >= need) {
        hipMemsetAsync(cursor, 0, NBINS * sizeof(int), stream);
        k_scatter<<<dim3(1024), dim3(256), 0, stream>>>(coords, bins, cursor, N);
        k_main<true><<<dim3(NXCD * BINS_PER_XCD * TILES_PER_BIN), dim3(128), 0, stream>>>(
            coords, bins, cursor, planeT, W1b, W2b, b1, b2, W3, b3, out, N);
    } else {
        k_main<false><<<dim3((N + 31) / 32), dim3(128), 0, stream>>>(
            coords, bins, cursor, planeT, W1b, W2b, b1, b2, W3, b3, out, N);
    }
}

// Round 6
// 395.261 us; speedup vs baseline: 1.3136x; 1.3136x over previous
//
#include <hip/hip_runtime.h>
#include <hip/hip_fp16.h>

typedef float f32x4 __attribute__((ext_vector_type(4)));
typedef __bf16 bf16x8 __attribute__((ext_vector_type(8)));

#define CDIM 128
#define HW 256

static __device__ __forceinline__ unsigned short f2bf(float f) {
    unsigned u = __builtin_bit_cast(unsigned, f);
    u += 0x7FFFu + ((u >> 16) & 1u);
    return (unsigned short)(u >> 16);
}

// ---- kernel 1: transpose plane (C,H,W) f32 -> (H,W,C) f16 ----
__global__ __launch_bounds__(256) void k_transpose(const float* __restrict__ plane,
                                                   unsigned short* __restrict__ planeT) {
    __shared__ unsigned short tile[32][130];
    int tid = threadIdx.x;
    int y  = blockIdx.x >> 3;
    int x0 = (blockIdx.x & 7) * 32;
    int tx = tid & 31, tc = tid >> 5;
    for (int cc = 0; cc < 128; cc += 8) {
        int c = cc + tc;
        float v = plane[c * (HW * HW) + y * HW + x0 + tx];
        tile[tx][c] = __half_as_ushort(__float2half(v));
    }
    __syncthreads();
    for (int it = 0; it < 16; ++it) {
        int idx = it * 256 + tid;
        int c = idx & 127, xi = idx >> 7;
        planeT[(y * HW + x0 + xi) * CDIM + c] = tile[xi][c];
    }
}

// ---- kernel 2: convert W1,W2 f32 -> bf16 ----
__global__ __launch_bounds__(256) void k_wconv(const float* __restrict__ W1,
                                               const float* __restrict__ W2,
                                               unsigned short* __restrict__ W1b,
                                               unsigned short* __restrict__ W2b) {
    int i = blockIdx.x * 256 + threadIdx.x;
    if (i < 16384) W1b[i] = f2bf(W1[i]);
    else           W2b[i - 16384] = f2bf(W2[i - 16384]);
}

// ---- gather helpers ((H,W,C) y-major layout, as in passing R4) ----
struct PrepT {
    int off[8];     // element offsets of the 8 corner rows (incl. lane ch-group)
    float w[8];     // xy weights [0..3]; xz weights [4..7]
};

__device__ __forceinline__ PrepT prep(const float* __restrict__ coords, int p, int cg) {
    PrepT r;
    float gx = coords[p * 3 + 0];
    float gy = coords[p * 3 + 1];
    float gz = coords[p * 3 + 2];
    float ix = (gx + 1.f) * 127.5f;
    float iy = (gy + 1.f) * 127.5f;
    float iz = (gz + 1.f) * 127.5f;
    float xf = floorf(ix), yf = floorf(iy), zf = floorf(iz);
    float wx1 = ix - xf, wy1 = iy - yf, wz1 = iz - zf;
    float wx0 = 1.f - wx1, wy0 = 1.f - wy1, wz0 = 1.f - wz1;
    int x0 = max(0, min((int)xf, HW - 1));
    int y0 = max(0, min((int)yf, HW - 1));
    int z0 = max(0, min((int)zf, HW - 1));
    int x1 = min(x0 + 1, HW - 1);
    int y1 = min(y0 + 1, HW - 1);
    int z1 = min(z0 + 1, HW - 1);
    int cx0 = x0 * CDIM + cg * 8, cx1 = x1 * CDIM + cg * 8;
    r.off[0] = (y0 << 15) + cx0; r.off[1] = (y0 << 15) + cx1;
    r.off[2] = (y1 << 15) + cx0; r.off[3] = (y1 << 15) + cx1;
    r.off[4] = (z0 << 15) + cx0; r.off[5] = (z0 << 15) + cx1;
    r.off[6] = (z1 << 15) + cx0; r.off[7] = (z1 << 15) + cx1;
    r.w[0] = wy0 * wx0; r.w[1] = wy0 * wx1; r.w[2] = wy1 * wx0; r.w[3] = wy1 * wx1;
    r.w[4] = wz0 * wx0; r.w[5] = wz0 * wx1; r.w[6] = wz1 * wx0; r.w[7] = wz1 * wx1;
    return r;
}

struct LdT { uint4 d[8]; };

__device__ __forceinline__ LdT ld8(const unsigned short* __restrict__ planeT, const PrepT& a) {
    LdT r;
#pragma unroll
    for (int c = 0; c < 8; ++c)
        r.d[c] = *reinterpret_cast<const uint4*>(planeT + a.off[c]);
    return r;
}

__device__ __forceinline__ void interp_store(unsigned short* dst, const PrepT& a, const LdT& L) {
    unsigned o[4];
#pragma unroll
    for (int g = 0; g < 4; ++g) {
        float2 v[8];
#pragma unroll
        for (int c = 0; c < 8; ++c) {
            unsigned wrd = reinterpret_cast<const unsigned*>(&L.d[c])[g];
            v[c] = __half22float2(__builtin_bit_cast(__half2, wrd));
        }
        float xy0 = a.w[0] * v[0].x + a.w[1] * v[1].x + a.w[2] * v[2].x + a.w[3] * v[3].x;
        float xy1 = a.w[0] * v[0].y + a.w[1] * v[1].y + a.w[2] * v[2].y + a.w[3] * v[3].y;
        float xz0 = a.w[4] * v[4].x + a.w[5] * v[5].x + a.w[6] * v[6].x + a.w[7] * v[7].x;
        float xz1 = a.w[4] * v[4].y + a.w[5] * v[5].y + a.w[6] * v[6].y + a.w[7] * v[7].y;
        float f0 = xy0 * xz0 * xz0;
        float f1 = xy1 * xz1 * xz1;
        o[g] = (unsigned)f2bf(f0) | ((unsigned)f2bf(f1) << 16);
    }
    uint4 pack; pack.x = o[0]; pack.y = o[1]; pack.z = o[2]; pack.w = o[3];
    *reinterpret_cast<uint4*>(dst) = pack;
}

// ---- kernel 3a: pure gather+interp -> feat[p][c] bf16 (global) ----
// 256 threads = 4 waves; wave handles 32 points (4/iter x 8 iters, depth-2).
// No LDS, no barriers, no MFMA: isolates the gather phase.
__global__ __launch_bounds__(256) void k_sample(const float* __restrict__ coords,
                                                const unsigned short* __restrict__ planeT,
                                                unsigned short* __restrict__ feat, int N) {
    const int wave = threadIdx.x >> 6, lane = threadIdx.x & 63;
    const int pt = lane >> 4, cg = lane & 15;
    const int base = blockIdx.x * 128 + wave * 32;

    PrepT a0 = prep(coords, min(base + pt, N - 1), cg);
    LdT   d0 = ld8(planeT, a0);
#pragma unroll
    for (int it = 0; it < 7; ++it) {
        PrepT a1 = prep(coords, min(base + (it + 1) * 4 + pt, N - 1), cg);
        LdT   d1 = ld8(planeT, a1);
        int p = min(base + it * 4 + pt, N - 1);
        interp_store(feat + (size_t)p * CDIM + cg * 8, a0, d0);
        a0 = a1; d0 = d1;
    }
    {
        int p = min(base + 28 + pt, N - 1);
        interp_store(feat + (size_t)p * CDIM + cg * 8, a0, d0);
    }
}

// ---- kernel 3b: batched MLP: out = (sin(30*(sin(30*(F@W1^T+b1))@W2^T+b2)))@W3^T+b3 ----
// 256 threads = 4 waves; block owns 64 points (16/wave). A-fragments loaded
// coalesced straight from feat (no LDS); one LDS round-trip for h1.
__global__ __launch_bounds__(256) void k_mlp(const unsigned short* __restrict__ feat,
                                             const unsigned short* __restrict__ W1b,
                                             const unsigned short* __restrict__ W2b,
                                             const float* __restrict__ b1,
                                             const float* __restrict__ b2,
                                             const float* __restrict__ W3,
                                             const float* __restrict__ b3,
                                             float* __restrict__ out, int N) {
    __shared__ alignas(16) unsigned short h1s[64][136];

    const int wave = threadIdx.x >> 6, lane = threadIdx.x & 63;
    const int ro   = wave * 16;
    const int pbase = blockIdx.x * 64 + ro;
    const int j = lane & 15, rg = lane >> 4;

    // -------- GEMM1 --------
    f32x4 acc[8];
#pragma unroll
    for (int nt = 0; nt < 8; ++nt) acc[nt] = (f32x4){0.f, 0.f, 0.f, 0.f};

    const size_t arow = (size_t)min(pbase + j, N - 1) * CDIM;
#pragma unroll
    for (int kk = 0; kk < 4; ++kk) {
        bf16x8 a = __builtin_bit_cast(bf16x8, *reinterpret_cast<const uint4*>(feat + arow + kk * 32 + rg * 8));
#pragma unroll
        for (int nt = 0; nt < 8; ++nt) {
            bf16x8 b = __builtin_bit_cast(bf16x8, *reinterpret_cast<const uint4*>(W1b + (nt * 16 + j) * 128 + kk * 32 + rg * 8));
            acc[nt] = __builtin_amdgcn_mfma_f32_16x16x32_bf16(a, b, acc[nt], 0, 0, 0);
        }
    }

#pragma unroll
    for (int nt = 0; nt < 8; ++nt) {
        float bb = b1[nt * 16 + j];
#pragma unroll
        for (int r = 0; r < 4; ++r) {
            float h = __sinf(30.f * (acc[nt][r] + bb));
            h1s[ro + rg * 4 + r][nt * 16 + j] = f2bf(h);
        }
    }

    __syncthreads();   // order h1s ds_writes before GEMM2 ds_reads (R2/R3 lesson)

    // -------- GEMM2 --------
    f32x4 acc2[8];
#pragma unroll
    for (int nt = 0; nt < 8; ++nt) acc2[nt] = (f32x4){0.f, 0.f, 0.f, 0.f};

#pragma unroll
    for (int kk = 0; kk < 4; ++kk) {
        bf16x8 a = __builtin_bit_cast(bf16x8, *reinterpret_cast<const uint4*>(&h1s[ro + j][kk * 32 + rg * 8]));
#pragma unroll
        for (int nt = 0; nt < 8; ++nt) {
            bf16x8 b = __builtin_bit_cast(bf16x8, *reinterpret_cast<const uint4*>(W2b + (nt * 16 + j) * 128 + kk * 32 + rg * 8));
            acc2[nt] = __builtin_amdgcn_mfma_f32_16x16x32_bf16(a, b, acc2[nt], 0, 0, 0);
        }
    }

    // -------- epilogue: out = h2 @ W3^T + b3 --------
    float part[4] = {0.f, 0.f, 0.f, 0.f};
#pragma unroll
    for (int nt = 0; nt < 8; ++nt) {
        float bb = b2[nt * 16 + j];
        float w3 = W3[nt * 16 + j];
#pragma unroll
        for (int r = 0; r < 4; ++r)
            part[r] += __sinf(30.f * (acc2[nt][r] + bb)) * w3;
    }
#pragma unroll
    for (int off = 1; off < 16; off <<= 1) {
#pragma unroll
        for (int r = 0; r < 4; ++r) part[r] += __shfl_xor(part[r], off, 64);
    }
    if (j == 0) {
        float bb3 = b3[0];
#pragma unroll
        for (int r = 0; r < 4; ++r) {
            int p = pbase + rg * 4 + r;
            if (p < N) out[p] = part[r] + bb3;
        }
    }
}

// ---- fallback: fused kernel (R4, proven) when ws can't hold feat ----
__global__ __launch_bounds__(128) void k_fused(const float* __restrict__ coords,
                                               const unsigned short* __restrict__ planeT,
                                               const unsigned short* __restrict__ W1b,
                                               const unsigned short* __restrict__ W2b,
                                               const float* __restrict__ b1,
                                               const float* __restrict__ b2,
                                               const float* __restrict__ W3,
                                               const float* __restrict__ b3,
                                               float* __restrict__ out, int N) {
    __shared__ alignas(16) unsigned short feat[32][136];
    __shared__ alignas(16) unsigned short h1s[32][136];

    const int tid  = threadIdx.x;
    const int wave = tid >> 6, lane = tid & 63;
    const int ro   = wave * 16;
    const int pbase = blockIdx.x * 32 + ro;

    {
        const int pt = lane >> 4, cg = lane & 15;
#pragma unroll
        for (int it = 0; it < 4; ++it) {
            int pl = it * 4 + pt;
            int p = min(pbase + pl, N - 1);
            PrepT a = prep(coords, p, cg);
            LdT   d = ld8(planeT, a);
            interp_store(&feat[ro + pl][cg * 8], a, d);
        }
    }
    __syncthreads();

    const int j = lane & 15, rg = lane >> 4;
    f32x4 acc[8];
#pragma unroll
    for (int nt = 0; nt < 8; ++nt) acc[nt] = (f32x4){0.f, 0.f, 0.f, 0.f};
#pragma unroll
    for (int kk = 0; kk < 4; ++kk) {
        bf16x8 a = __builtin_bit_cast(bf16x8, *reinterpret_cast<const uint4*>(&feat[ro + j][kk * 32 + rg * 8]));
#pragma unroll
        for (int nt = 0; nt < 8; ++nt) {
            bf16x8 b = __builtin_bit_cast(bf16x8, *reinterpret_cast<const uint4*>(W1b + (nt * 16 + j) * 128 + kk * 32 + rg * 8));
            acc[nt] = __builtin_amdgcn_mfma_f32_16x16x32_bf16(a, b, acc[nt], 0, 0, 0);
        }
    }
#pragma unroll
    for (int nt = 0; nt < 8; ++nt) {
        float bb = b1[nt * 16 + j];
#pragma unroll
        for (int r = 0; r < 4; ++r) {
            float h = __sinf(30.f * (acc[nt][r] + bb));
            h1s[ro + rg * 4 + r][nt * 16 + j] = f2bf(h);
        }
    }
    __syncthreads();

    f32x4 acc2[8];
#pragma unroll
    for (int nt = 0; nt < 8; ++nt) acc2[nt] = (f32x4){0.f, 0.f, 0.f, 0.f};
#pragma unroll
    for (int kk = 0; kk < 4; ++kk) {
        bf16x8 a = __builtin_bit_cast(bf16x8, *reinterpret_cast<const uint4*>(&h1s[ro + j][kk * 32 + rg * 8]));
#pragma unroll
        for (int nt = 0; nt < 8; ++nt) {
            bf16x8 b = __builtin_bit_cast(bf16x8, *reinterpret_cast<const uint4*>(W2b + (nt * 16 + j) * 128 + kk * 32 + rg * 8));
            acc2[nt] = __builtin_amdgcn_mfma_f32_16x16x32_bf16(a, b, acc2[nt], 0, 0, 0);
        }
    }

    float part[4] = {0.f, 0.f, 0.f, 0.f};
#pragma unroll
    for (int nt = 0; nt < 8; ++nt) {
        float bb = b2[nt * 16 + j];
        float w3 = W3[nt * 16 + j];
#pragma unroll
        for (int r = 0; r < 4; ++r)
            part[r] += __sinf(30.f * (acc2[nt][r] + bb)) * w3;
    }
#pragma unroll
    for (int off = 1; off < 16; off <<= 1) {
#pragma unroll
        for (int r = 0; r < 4; ++r) part[r] += __shfl_xor(part[r], off, 64);
    }
    if (j == 0) {
        float bb3 = b3[0];
#pragma unroll
        for (int r = 0; r < 4; ++r) {
            int p = pbase + rg * 4 + r;
            if (p < N) out[p] = part[r] + bb3;
        }
    }
}

extern "C" void kernel_launch(void* const* d_in, const int* in_sizes, int n_in,
                              void* d_out, int out_size, void* d_ws, size_t ws_size,
                              hipStream_t stream) {
    const float* coords = (const float*)d_in[0];
    const float* plane  = (const float*)d_in[1];
    const float* W1     = (const float*)d_in[4];
    const float* b1     = (const float*)d_in[5];
    const float* W2     = (const float*)d_in[6];
    const float* b2     = (const float*)d_in[7];
    const float* W3     = (const float*)d_in[8];
    const float* b3     = (const float*)d_in[9];
    float* out = (float*)d_out;
    int N = in_sizes[0] / 3;

    char* ws = (char*)d_ws;
    unsigned short* planeT = (unsigned short*)ws;                      // 16 MB
    unsigned short* W1b = (unsigned short*)(ws + 16777216);            // 32 KB
    unsigned short* W2b = (unsigned short*)(ws + 16809984);            // 32 KB
    unsigned short* feat = (unsigned short*)(ws + 16842752);           // 128 MB
    const size_t need = 16842752 + (size_t)N * CDIM * 2;

    k_transpose<<<dim3(HW * 8), dim3(256), 0, stream>>>(plane, planeT);
    k_wconv<<<dim3(128), dim3(256), 0, stream>>>(W1, W2, W1b, W2b);

    if (ws_size >= need) {
        k_sample<<<dim3((N + 127) / 128), dim3(256), 0, stream>>>(coords, planeT, feat, N);
        k_mlp<<<dim3((N + 63) / 64), dim3(256), 0, stream>>>(feat, W1b, W2b, b1, b2, W3, b3, out, N);
    } else {
        k_fused<<<dim3((N + 31) / 32), dim3(128), 0, stream>>>(coords, planeT, W1b, W2b,
                                                               b1, b2, W3, b3, out, N);
    }
}

// Round 7
// 211.090 us; speedup vs baseline: 2.4597x; 1.8725x over previous
//
#include <hip/hip_runtime.h>
#include <hip/hip_fp16.h>

typedef float f32x4 __attribute__((ext_vector_type(4)));
typedef __bf16 bf16x8 __attribute__((ext_vector_type(8)));

#define CDIM 128
#define HW 256

static __device__ __forceinline__ unsigned short f2bf(float f) {
    unsigned u = __builtin_bit_cast(unsigned, f);
    u += 0x7FFFu + ((u >> 16) & 1u);
    return (unsigned short)(u >> 16);
}

// ---- kernel 1: transpose plane (C,H,W) f32 -> (H,W,C) f16 ----
__global__ __launch_bounds__(256) void k_transpose(const float* __restrict__ plane,
                                                   unsigned short* __restrict__ planeT) {
    __shared__ unsigned short tile[32][130];
    int tid = threadIdx.x;
    int y  = blockIdx.x >> 3;
    int x0 = (blockIdx.x & 7) * 32;
    int tx = tid & 31, tc = tid >> 5;
    for (int cc = 0; cc < 128; cc += 8) {
        int c = cc + tc;
        float v = plane[c * (HW * HW) + y * HW + x0 + tx];
        tile[tx][c] = __half_as_ushort(__float2half(v));
    }
    __syncthreads();
    for (int it = 0; it < 16; ++it) {
        int idx = it * 256 + tid;
        int c = idx & 127, xi = idx >> 7;
        planeT[(y * HW + x0 + xi) * CDIM + c] = tile[xi][c];
    }
}

// ---- kernel 2: convert W1,W2 f32 -> bf16 ----
__global__ __launch_bounds__(256) void k_wconv(const float* __restrict__ W1,
                                               const float* __restrict__ W2,
                                               unsigned short* __restrict__ W1b,
                                               unsigned short* __restrict__ W2b) {
    int i = blockIdx.x * 256 + threadIdx.x;
    if (i < 16384) W1b[i] = f2bf(W1[i]);
    else           W2b[i - 16384] = f2bf(W2[i - 16384]);
}

// ---- gather helpers ((H,W,C) y-major layout) ----
struct PrepT {
    int off[8];
    float w[8];
};

__device__ __forceinline__ PrepT prep(const float* __restrict__ coords, int p, int cg) {
    PrepT r;
    float gx = coords[p * 3 + 0];
    float gy = coords[p * 3 + 1];
    float gz = coords[p * 3 + 2];
    float ix = (gx + 1.f) * 127.5f;
    float iy = (gy + 1.f) * 127.5f;
    float iz = (gz + 1.f) * 127.5f;
    float xf = floorf(ix), yf = floorf(iy), zf = floorf(iz);
    float wx1 = ix - xf, wy1 = iy - yf, wz1 = iz - zf;
    float wx0 = 1.f - wx1, wy0 = 1.f - wy1, wz0 = 1.f - wz1;
    int x0 = max(0, min((int)xf, HW - 1));
    int y0 = max(0, min((int)yf, HW - 1));
    int z0 = max(0, min((int)zf, HW - 1));
    int x1 = min(x0 + 1, HW - 1);
    int y1 = min(y0 + 1, HW - 1);
    int z1 = min(z0 + 1, HW - 1);
    int cx0 = x0 * CDIM + cg * 8, cx1 = x1 * CDIM + cg * 8;
    r.off[0] = (y0 << 15) + cx0; r.off[1] = (y0 << 15) + cx1;
    r.off[2] = (y1 << 15) + cx0; r.off[3] = (y1 << 15) + cx1;
    r.off[4] = (z0 << 15) + cx0; r.off[5] = (z0 << 15) + cx1;
    r.off[6] = (z1 << 15) + cx0; r.off[7] = (z1 << 15) + cx1;
    r.w[0] = wy0 * wx0; r.w[1] = wy0 * wx1; r.w[2] = wy1 * wx0; r.w[3] = wy1 * wx1;
    r.w[4] = wz0 * wx0; r.w[5] = wz0 * wx1; r.w[6] = wz1 * wx0; r.w[7] = wz1 * wx1;
    return r;
}

struct LdT { uint4 d[8]; };

__device__ __forceinline__ LdT ld8(const unsigned short* __restrict__ planeT, const PrepT& a) {
    LdT r;
#pragma unroll
    for (int c = 0; c < 8; ++c)
        r.d[c] = *reinterpret_cast<const uint4*>(planeT + a.off[c]);
    return r;
}

__device__ __forceinline__ void interp_store(unsigned short* dst, const PrepT& a, const LdT& L) {
    unsigned o[4];
#pragma unroll
    for (int g = 0; g < 4; ++g) {
        float2 v[8];
#pragma unroll
        for (int c = 0; c < 8; ++c) {
            unsigned wrd = reinterpret_cast<const unsigned*>(&L.d[c])[g];
            v[c] = __half22float2(__builtin_bit_cast(__half2, wrd));
        }
        float xy0 = a.w[0] * v[0].x + a.w[1] * v[1].x + a.w[2] * v[2].x + a.w[3] * v[3].x;
        float xy1 = a.w[0] * v[0].y + a.w[1] * v[1].y + a.w[2] * v[2].y + a.w[3] * v[3].y;
        float xz0 = a.w[4] * v[4].x + a.w[5] * v[5].x + a.w[6] * v[6].x + a.w[7] * v[7].x;
        float xz1 = a.w[4] * v[4].y + a.w[5] * v[5].y + a.w[6] * v[6].y + a.w[7] * v[7].y;
        float f0 = xy0 * xz0 * xz0;
        float f1 = xy1 * xz1 * xz1;
        o[g] = (unsigned)f2bf(f0) | ((unsigned)f2bf(f1) << 16);
    }
    uint4 pack; pack.x = o[0]; pack.y = o[1]; pack.z = o[2]; pack.w = o[3];
    *reinterpret_cast<uint4*>(dst) = pack;
}

// ---- kernel 3a: pure gather+interp -> feat[p][c] bf16 (global) ----
__global__ __launch_bounds__(256) void k_sample(const float* __restrict__ coords,
                                                const unsigned short* __restrict__ planeT,
                                                unsigned short* __restrict__ feat, int N) {
    const int wave = threadIdx.x >> 6, lane = threadIdx.x & 63;
    const int pt = lane >> 4, cg = lane & 15;
    const int base = blockIdx.x * 128 + wave * 32;

    PrepT a0 = prep(coords, min(base + pt, N - 1), cg);
    LdT   d0 = ld8(planeT, a0);
#pragma unroll
    for (int it = 0; it < 7; ++it) {
        PrepT a1 = prep(coords, min(base + (it + 1) * 4 + pt, N - 1), cg);
        LdT   d1 = ld8(planeT, a1);
        int p = min(base + it * 4 + pt, N - 1);
        interp_store(feat + (size_t)p * CDIM + cg * 8, a0, d0);
        a0 = a1; d0 = d1;
    }
    {
        int p = min(base + 28 + pt, N - 1);
        interp_store(feat + (size_t)p * CDIM + cg * 8, a0, d0);
    }
}

// ---- kernel 3b: batched MLP as a real GEMM ----
// 512 threads = 8 waves; W1+W2 staged ONCE per block into LDS (XOR-swizzled
// 16B columns: row stride 256B would put all same-rg lanes in one bank).
// Grid-stride over 128-point tiles amortizes staging (~16 tiles/block).
// R6 post-mortem: W fragments from global were loaded just-in-time (VGPR=48),
// serializing every MFMA on ~300cyc L2 latency -> 264us. B-frags now come
// from LDS, batched 8 ahead of the MFMAs.
__global__ __launch_bounds__(512, 2) void k_mlp(const unsigned short* __restrict__ feat,
                                                const unsigned short* __restrict__ W1b,
                                                const unsigned short* __restrict__ W2b,
                                                const float* __restrict__ b1,
                                                const float* __restrict__ b2,
                                                const float* __restrict__ W3,
                                                const float* __restrict__ b3,
                                                float* __restrict__ out, int N) {
    __shared__ alignas(16) uint4 W1L[128][16];            // 32 KB, swizzled
    __shared__ alignas(16) uint4 W2L[128][16];            // 32 KB, swizzled
    __shared__ alignas(16) unsigned short h1s[128][136];  // 34.8 KB, wave-private rows

    const int tid  = threadIdx.x;
    const int wave = tid >> 6, lane = tid & 63;
    const int ro   = wave * 16;
    const int j = lane & 15, rg = lane >> 4;

    // stage W into LDS (coalesced global read, swizzled LDS write)
#pragma unroll
    for (int i = 0; i < 4; ++i) {
        int idx = i * 512 + tid;
        int row = idx >> 4, col = idx & 15;
        W1L[row][col ^ (row & 15)] = reinterpret_cast<const uint4*>(W1b)[idx];
        W2L[row][col ^ (row & 15)] = reinterpret_cast<const uint4*>(W2b)[idx];
    }
    float b1v[8], b2v[8], w3v[8];
#pragma unroll
    for (int nt = 0; nt < 8; ++nt) {
        b1v[nt] = b1[nt * 16 + j];
        b2v[nt] = b2[nt * 16 + j];
        w3v[nt] = W3[nt * 16 + j];
    }
    const float bb3 = b3[0];
    __syncthreads();

    const int ntiles = (N + 127) >> 7;
    for (int t = blockIdx.x; t < ntiles; t += gridDim.x) {
        const int pbase = t * 128 + ro;

        // -------- GEMM1: h1 = sin(30*(feat @ W1^T + b1)) --------
        f32x4 acc[8];
#pragma unroll
        for (int nt = 0; nt < 8; ++nt) acc[nt] = (f32x4){0.f, 0.f, 0.f, 0.f};

        const size_t arow = (size_t)min(pbase + j, N - 1) * CDIM;
        bf16x8 af[4];
#pragma unroll
        for (int kk = 0; kk < 4; ++kk)
            af[kk] = __builtin_bit_cast(bf16x8, *reinterpret_cast<const uint4*>(feat + arow + kk * 32 + rg * 8));

#pragma unroll
        for (int kk = 0; kk < 4; ++kk) {
            bf16x8 bf[8];
#pragma unroll
            for (int nt = 0; nt < 8; ++nt)
                bf[nt] = __builtin_bit_cast(bf16x8, W1L[nt * 16 + j][(kk * 4 + rg) ^ j]);
#pragma unroll
            for (int nt = 0; nt < 8; ++nt)
                acc[nt] = __builtin_amdgcn_mfma_f32_16x16x32_bf16(af[kk], bf[nt], acc[nt], 0, 0, 0);
        }

#pragma unroll
        for (int nt = 0; nt < 8; ++nt) {
#pragma unroll
            for (int r = 0; r < 4; ++r) {
                float h = __sinf(30.f * (acc[nt][r] + b1v[nt]));
                h1s[ro + rg * 4 + r][nt * 16 + j] = f2bf(h);
            }
        }

        __syncthreads();   // order h1s ds_writes before GEMM2 ds_reads

        // -------- GEMM2: h2 = sin(30*(h1 @ W2^T + b2)) --------
        f32x4 acc2[8];
#pragma unroll
        for (int nt = 0; nt < 8; ++nt) acc2[nt] = (f32x4){0.f, 0.f, 0.f, 0.f};

        bf16x8 af2[4];
#pragma unroll
        for (int kk = 0; kk < 4; ++kk)
            af2[kk] = __builtin_bit_cast(bf16x8, *reinterpret_cast<const uint4*>(&h1s[ro + j][kk * 32 + rg * 8]));

#pragma unroll
        for (int kk = 0; kk < 4; ++kk) {
            bf16x8 bf[8];
#pragma unroll
            for (int nt = 0; nt < 8; ++nt)
                bf[nt] = __builtin_bit_cast(bf16x8, W2L[nt * 16 + j][(kk * 4 + rg) ^ j]);
#pragma unroll
            for (int nt = 0; nt < 8; ++nt)
                acc2[nt] = __builtin_amdgcn_mfma_f32_16x16x32_bf16(af2[kk], bf[nt], acc2[nt], 0, 0, 0);
        }

        // -------- epilogue: out = h2 @ W3^T + b3 --------
        float part[4] = {0.f, 0.f, 0.f, 0.f};
#pragma unroll
        for (int nt = 0; nt < 8; ++nt) {
#pragma unroll
            for (int r = 0; r < 4; ++r)
                part[r] += __sinf(30.f * (acc2[nt][r] + b2v[nt])) * w3v[nt];
        }
#pragma unroll
        for (int off = 1; off < 16; off <<= 1) {
#pragma unroll
            for (int r = 0; r < 4; ++r) part[r] += __shfl_xor(part[r], off, 64);
        }
        if (j == 0) {
#pragma unroll
            for (int r = 0; r < 4; ++r) {
                int p = pbase + rg * 4 + r;
                if (p < N) out[p] = part[r] + bb3;
            }
        }

        __syncthreads();   // protect h1s reads from next tile's writes
    }
}

// ---- fallback: fused kernel (R4, proven) when ws can't hold feat ----
__global__ __launch_bounds__(128) void k_fused(const float* __restrict__ coords,
                                               const unsigned short* __restrict__ planeT,
                                               const unsigned short* __restrict__ W1b,
                                               const unsigned short* __restrict__ W2b,
                                               const float* __restrict__ b1,
                                               const float* __restrict__ b2,
                                               const float* __restrict__ W3,
                                               const float* __restrict__ b3,
                                               float* __restrict__ out, int N) {
    __shared__ alignas(16) unsigned short feat[32][136];
    __shared__ alignas(16) unsigned short h1s[32][136];

    const int tid  = threadIdx.x;
    const int wave = tid >> 6, lane = tid & 63;
    const int ro   = wave * 16;
    const int pbase = blockIdx.x * 32 + ro;

    {
        const int pt = lane >> 4, cg = lane & 15;
#pragma unroll
        for (int it = 0; it < 4; ++it) {
            int pl = it * 4 + pt;
            int p = min(pbase + pl, N - 1);
            PrepT a = prep(coords, p, cg);
            LdT   d = ld8(planeT, a);
            interp_store(&feat[ro + pl][cg * 8], a, d);
        }
    }
    __syncthreads();

    const int j = lane & 15, rg = lane >> 4;
    f32x4 acc[8];
#pragma unroll
    for (int nt = 0; nt < 8; ++nt) acc[nt] = (f32x4){0.f, 0.f, 0.f, 0.f};
#pragma unroll
    for (int kk = 0; kk < 4; ++kk) {
        bf16x8 a = __builtin_bit_cast(bf16x8, *reinterpret_cast<const uint4*>(&feat[ro + j][kk * 32 + rg * 8]));
#pragma unroll
        for (int nt = 0; nt < 8; ++nt) {
            bf16x8 b = __builtin_bit_cast(bf16x8, *reinterpret_cast<const uint4*>(W1b + (nt * 16 + j) * 128 + kk * 32 + rg * 8));
            acc[nt] = __builtin_amdgcn_mfma_f32_16x16x32_bf16(a, b, acc[nt], 0, 0, 0);
        }
    }
#pragma unroll
    for (int nt = 0; nt < 8; ++nt) {
        float bb = b1[nt * 16 + j];
#pragma unroll
        for (int r = 0; r < 4; ++r) {
            float h = __sinf(30.f * (acc[nt][r] + bb));
            h1s[ro + rg * 4 + r][nt * 16 + j] = f2bf(h);
        }
    }
    __syncthreads();

    f32x4 acc2[8];
#pragma unroll
    for (int nt = 0; nt < 8; ++nt) acc2[nt] = (f32x4){0.f, 0.f, 0.f, 0.f};
#pragma unroll
    for (int kk = 0; kk < 4; ++kk) {
        bf16x8 a = __builtin_bit_cast(bf16x8, *reinterpret_cast<const uint4*>(&h1s[ro + j][kk * 32 + rg * 8]));
#pragma unroll
        for (int nt = 0; nt < 8; ++nt) {
            bf16x8 b = __builtin_bit_cast(bf16x8, *reinterpret_cast<const uint4*>(W2b + (nt * 16 + j) * 128 + kk * 32 + rg * 8));
            acc2[nt] = __builtin_amdgcn_mfma_f32_16x16x32_bf16(a, b, acc2[nt], 0, 0, 0);
        }
    }

    float part[4] = {0.f, 0.f, 0.f, 0.f};
#pragma unroll
    for (int nt = 0; nt < 8; ++nt) {
        float bb = b2[nt * 16 + j];
        float w3 = W3[nt * 16 + j];
#pragma unroll
        for (int r = 0; r < 4; ++r)
            part[r] += __sinf(30.f * (acc2[nt][r] + bb)) * w3;
    }
#pragma unroll
    for (int off = 1; off < 16; off <<= 1) {
#pragma unroll
        for (int r = 0; r < 4; ++r) part[r] += __shfl_xor(part[r], off, 64);
    }
    if (j == 0) {
        float bb3 = b3[0];
#pragma unroll
        for (int r = 0; r < 4; ++r) {
            int p = pbase + rg * 4 + r;
            if (p < N) out[p] = part[r] + bb3;
        }
    }
}

extern "C" void kernel_launch(void* const* d_in, const int* in_sizes, int n_in,
                              void* d_out, int out_size, void* d_ws, size_t ws_size,
                              hipStream_t stream) {
    const float* coords = (const float*)d_in[0];
    const float* plane  = (const float*)d_in[1];
    const float* W1     = (const float*)d_in[4];
    const float* b1     = (const float*)d_in[5];
    const float* W2     = (const float*)d_in[6];
    const float* b2     = (const float*)d_in[7];
    const float* W3     = (const float*)d_in[8];
    const float* b3     = (const float*)d_in[9];
    float* out = (float*)d_out;
    int N = in_sizes[0] / 3;

    char* ws = (char*)d_ws;
    unsigned short* planeT = (unsigned short*)ws;                      // 16 MB
    unsigned short* W1b = (unsigned short*)(ws + 16777216);            // 32 KB
    unsigned short* W2b = (unsigned short*)(ws + 16809984);            // 32 KB
    unsigned short* feat = (unsigned short*)(ws + 16842752);           // 128 MB
    const size_t need = 16842752 + (size_t)N * CDIM * 2;

    k_transpose<<<dim3(HW * 8), dim3(256), 0, stream>>>(plane, planeT);
    k_wconv<<<dim3(128), dim3(256), 0, stream>>>(W1, W2, W1b, W2b);

    if (ws_size >= need) {
        k_sample<<<dim3((N + 127) / 128), dim3(256), 0, stream>>>(coords, planeT, feat, N);
        k_mlp<<<dim3(256), dim3(512), 0, stream>>>(feat, W1b, W2b, b1, b2, W3, b3, out, N);
    } else {
        k_fused<<<dim3((N + 31) / 32), dim3(128), 0, stream>>>(coords, planeT, W1b, W2b,
                                                               b1, b2, W3, b3, out, N);
    }
}

// Round 8
// 136.806 us; speedup vs baseline: 3.7953x; 1.5430x over previous
//
#include <hip/hip_runtime.h>
#include <hip/hip_fp16.h>

typedef float f32x4 __attribute__((ext_vector_type(4)));
typedef __bf16 bf16x8 __attribute__((ext_vector_type(8)));

#define CDIM 128
#define HW 256

static __device__ __forceinline__ unsigned short f2bf(float f) {
    unsigned u = __builtin_bit_cast(unsigned, f);
    u += 0x7FFFu + ((u >> 16) & 1u);
    return (unsigned short)(u >> 16);
}

// ---- kernel 1: transpose plane (C,H,W) f32 -> (H,W,C) f16 ----
__global__ __launch_bounds__(256) void k_transpose(const float* __restrict__ plane,
                                                   unsigned short* __restrict__ planeT) {
    __shared__ unsigned short tile[32][130];
    int tid = threadIdx.x;
    int y  = blockIdx.x >> 3;
    int x0 = (blockIdx.x & 7) * 32;
    int tx = tid & 31, tc = tid >> 5;
    for (int cc = 0; cc < 128; cc += 8) {
        int c = cc + tc;
        float v = plane[c * (HW * HW) + y * HW + x0 + tx];
        tile[tx][c] = __half_as_ushort(__float2half(v));
    }
    __syncthreads();
    for (int it = 0; it < 16; ++it) {
        int idx = it * 256 + tid;
        int c = idx & 127, xi = idx >> 7;
        planeT[(y * HW + x0 + xi) * CDIM + c] = tile[xi][c];
    }
}

// ---- kernel 2: convert W1,W2 f32 -> bf16 ----
__global__ __launch_bounds__(256) void k_wconv(const float* __restrict__ W1,
                                               const float* __restrict__ W2,
                                               unsigned short* __restrict__ W1b,
                                               unsigned short* __restrict__ W2b) {
    int i = blockIdx.x * 256 + threadIdx.x;
    if (i < 16384) W1b[i] = f2bf(W1[i]);
    else           W2b[i - 16384] = f2bf(W2[i - 16384]);
}

// ---- gather helpers ((H,W,C) y-major layout) ----
struct PrepT {
    int off[8];
    float w[8];
};

__device__ __forceinline__ PrepT prep(const float* __restrict__ coords, int p, int cg) {
    PrepT r;
    float gx = coords[p * 3 + 0];
    float gy = coords[p * 3 + 1];
    float gz = coords[p * 3 + 2];
    float ix = (gx + 1.f) * 127.5f;
    float iy = (gy + 1.f) * 127.5f;
    float iz = (gz + 1.f) * 127.5f;
    float xf = floorf(ix), yf = floorf(iy), zf = floorf(iz);
    float wx1 = ix - xf, wy1 = iy - yf, wz1 = iz - zf;
    float wx0 = 1.f - wx1, wy0 = 1.f - wy1, wz0 = 1.f - wz1;
    int x0 = max(0, min((int)xf, HW - 1));
    int y0 = max(0, min((int)yf, HW - 1));
    int z0 = max(0, min((int)zf, HW - 1));
    int x1 = min(x0 + 1, HW - 1);
    int y1 = min(y0 + 1, HW - 1);
    int z1 = min(z0 + 1, HW - 1);
    int cx0 = x0 * CDIM + cg * 8, cx1 = x1 * CDIM + cg * 8;
    r.off[0] = (y0 << 15) + cx0; r.off[1] = (y0 << 15) + cx1;
    r.off[2] = (y1 << 15) + cx0; r.off[3] = (y1 << 15) + cx1;
    r.off[4] = (z0 << 15) + cx0; r.off[5] = (z0 << 15) + cx1;
    r.off[6] = (z1 << 15) + cx0; r.off[7] = (z1 << 15) + cx1;
    r.w[0] = wy0 * wx0; r.w[1] = wy0 * wx1; r.w[2] = wy1 * wx0; r.w[3] = wy1 * wx1;
    r.w[4] = wz0 * wx0; r.w[5] = wz0 * wx1; r.w[6] = wz1 * wx0; r.w[7] = wz1 * wx1;
    return r;
}

struct LdT { uint4 d[8]; };

__device__ __forceinline__ LdT ld8(const unsigned short* __restrict__ planeT, const PrepT& a) {
    LdT r;
#pragma unroll
    for (int c = 0; c < 8; ++c)
        r.d[c] = *reinterpret_cast<const uint4*>(planeT + a.off[c]);
    return r;
}

__device__ __forceinline__ void interp_store(unsigned short* dst, const PrepT& a, const LdT& L) {
    unsigned o[4];
#pragma unroll
    for (int g = 0; g < 4; ++g) {
        float2 v[8];
#pragma unroll
        for (int c = 0; c < 8; ++c) {
            unsigned wrd = reinterpret_cast<const unsigned*>(&L.d[c])[g];
            v[c] = __half22float2(__builtin_bit_cast(__half2, wrd));
        }
        float xy0 = a.w[0] * v[0].x + a.w[1] * v[1].x + a.w[2] * v[2].x + a.w[3] * v[3].x;
        float xy1 = a.w[0] * v[0].y + a.w[1] * v[1].y + a.w[2] * v[2].y + a.w[3] * v[3].y;
        float xz0 = a.w[4] * v[4].x + a.w[5] * v[5].x + a.w[6] * v[6].x + a.w[7] * v[7].x;
        float xz1 = a.w[4] * v[4].y + a.w[5] * v[5].y + a.w[6] * v[6].y + a.w[7] * v[7].y;
        float f0 = xy0 * xz0 * xz0;
        float f1 = xy1 * xz1 * xz1;
        o[g] = (unsigned)f2bf(f0) | ((unsigned)f2bf(f1) << 16);
    }
    uint4 pack; pack.x = o[0]; pack.y = o[1]; pack.z = o[2]; pack.w = o[3];
    *reinterpret_cast<uint4*>(dst) = pack;
}

// ---- kernel 3: fully fused gather + MLP ----
// 256 threads = 4 waves; W1+W2 staged once per block into LDS (R7's proven
// swizzle); feat/h1 share a 16KB XOR-swizzled wave-private buffer. LDS = 80KB
// exactly -> 2 blocks/CU for cross-block gather/MFMA overlap. Grid-stride
// (~15 tiles/block) amortizes W staging. __syncthreads at every type-punned
// LDS producer->consumer edge (R2/R3 lesson).
__global__ __launch_bounds__(256, 2) void k_all(const float* __restrict__ coords,
                                                const unsigned short* __restrict__ planeT,
                                                const unsigned short* __restrict__ W1b,
                                                const unsigned short* __restrict__ W2b,
                                                const float* __restrict__ b1,
                                                const float* __restrict__ b2,
                                                const float* __restrict__ W3,
                                                const float* __restrict__ b3,
                                                float* __restrict__ out, int N) {
    __shared__ alignas(16) uint4 W1L[128][16];              // 32 KB, swizzled
    __shared__ alignas(16) uint4 W2L[128][16];              // 32 KB, swizzled
    __shared__ alignas(16) unsigned short featS[64][128];   // 16 KB, 16B-group swizzle

    const int tid  = threadIdx.x;
    const int wave = tid >> 6, lane = tid & 63;
    const int ro   = wave * 16;
    const int j = lane & 15, rg = lane >> 4;
    const int pt = lane >> 4, cg = lane & 15;   // gather roles

    // stage W into LDS (coalesced global read, swizzled LDS write)
#pragma unroll
    for (int i = 0; i < 8; ++i) {
        int idx = i * 256 + tid;
        int row = idx >> 4, col = idx & 15;
        W1L[row][col ^ (row & 15)] = reinterpret_cast<const uint4*>(W1b)[idx];
        W2L[row][col ^ (row & 15)] = reinterpret_cast<const uint4*>(W2b)[idx];
    }
    float b1v[8], b2v[8], w3v[8];
#pragma unroll
    for (int nt = 0; nt < 8; ++nt) {
        b1v[nt] = b1[nt * 16 + j];
        b2v[nt] = b2[nt * 16 + j];
        w3v[nt] = W3[nt * 16 + j];
    }
    const float bb3 = b3[0];
    __syncthreads();

    const int ntiles = (N + 63) >> 6;
    for (int t = blockIdx.x; t < ntiles; t += gridDim.x) {
        const int pbase = t * 64 + ro;

        // -------- phase A: gather 16 points/wave into swizzled featS --------
        {
            PrepT a0 = prep(coords, min(pbase + pt, N - 1), cg);
            LdT   d0 = ld8(planeT, a0);
#pragma unroll
            for (int it = 0; it < 3; ++it) {
                PrepT a1 = prep(coords, min(pbase + (it + 1) * 4 + pt, N - 1), cg);
                LdT   d1 = ld8(planeT, a1);
                int pl = it * 4 + pt;
                interp_store(&featS[ro + pl][(cg ^ pl) * 8], a0, d0);
                a0 = a1; d0 = d1;
            }
            int pl = 12 + pt;
            interp_store(&featS[ro + pl][(cg ^ pl) * 8], a0, d0);
        }

        __syncthreads();   // order feat ds_writes before GEMM1 ds_reads

        // -------- GEMM1: h1 = sin(30*(feat @ W1^T + b1)) --------
        f32x4 acc[8];
#pragma unroll
        for (int nt = 0; nt < 8; ++nt) acc[nt] = (f32x4){0.f, 0.f, 0.f, 0.f};

        bf16x8 af[4];
#pragma unroll
        for (int kk = 0; kk < 4; ++kk)
            af[kk] = __builtin_bit_cast(bf16x8, *reinterpret_cast<const uint4*>(&featS[ro + j][((kk * 4 + rg) ^ j) * 8]));

#pragma unroll
        for (int kk = 0; kk < 4; ++kk) {
            bf16x8 bf[8];
#pragma unroll
            for (int nt = 0; nt < 8; ++nt)
                bf[nt] = __builtin_bit_cast(bf16x8, W1L[nt * 16 + j][(kk * 4 + rg) ^ j]);
#pragma unroll
            for (int nt = 0; nt < 8; ++nt)
                acc[nt] = __builtin_amdgcn_mfma_f32_16x16x32_bf16(af[kk], bf[nt], acc[nt], 0, 0, 0);
        }

        // h1 overwrites featS rows (wave-private; af already consumed by MFMA)
#pragma unroll
        for (int nt = 0; nt < 8; ++nt) {
#pragma unroll
            for (int r = 0; r < 4; ++r) {
                float h = __sinf(30.f * (acc[nt][r] + b1v[nt]));
                int row = rg * 4 + r;
                int g = (nt * 2 + (j >> 3)) ^ row;
                featS[ro + row][g * 8 + (j & 7)] = f2bf(h);
            }
        }

        __syncthreads();   // order h1 ds_writes before GEMM2 ds_reads

        // -------- GEMM2: h2 = sin(30*(h1 @ W2^T + b2)) --------
        f32x4 acc2[8];
#pragma unroll
        for (int nt = 0; nt < 8; ++nt) acc2[nt] = (f32x4){0.f, 0.f, 0.f, 0.f};

        bf16x8 af2[4];
#pragma unroll
        for (int kk = 0; kk < 4; ++kk)
            af2[kk] = __builtin_bit_cast(bf16x8, *reinterpret_cast<const uint4*>(&featS[ro + j][((kk * 4 + rg) ^ j) * 8]));

#pragma unroll
        for (int kk = 0; kk < 4; ++kk) {
            bf16x8 bf[8];
#pragma unroll
            for (int nt = 0; nt < 8; ++nt)
                bf[nt] = __builtin_bit_cast(bf16x8, W2L[nt * 16 + j][(kk * 4 + rg) ^ j]);
#pragma unroll
            for (int nt = 0; nt < 8; ++nt)
                acc2[nt] = __builtin_amdgcn_mfma_f32_16x16x32_bf16(af2[kk], bf[nt], acc2[nt], 0, 0, 0);
        }

        // -------- epilogue: out = h2 @ W3^T + b3 --------
        float part[4] = {0.f, 0.f, 0.f, 0.f};
#pragma unroll
        for (int nt = 0; nt < 8; ++nt) {
#pragma unroll
            for (int r = 0; r < 4; ++r)
                part[r] += __sinf(30.f * (acc2[nt][r] + b2v[nt])) * w3v[nt];
        }
#pragma unroll
        for (int off = 1; off < 16; off <<= 1) {
#pragma unroll
            for (int r = 0; r < 4; ++r) part[r] += __shfl_xor(part[r], off, 64);
        }
        if (j == 0) {
#pragma unroll
            for (int r = 0; r < 4; ++r) {
                int p = pbase + rg * 4 + r;
                if (p < N) out[p] = part[r] + bb3;
            }
        }

        __syncthreads();   // protect featS reads from next tile's gather writes
    }
}

// ---- fallback: fused kernel (R4, proven) if ws can't hold planeT+W ----
__global__ __launch_bounds__(128) void k_fused(const float* __restrict__ coords,
                                               const unsigned short* __restrict__ planeT,
                                               const unsigned short* __restrict__ W1b,
                                               const unsigned short* __restrict__ W2b,
                                               const float* __restrict__ b1,
                                               const float* __restrict__ b2,
                                               const float* __restrict__ W3,
                                               const float* __restrict__ b3,
                                               float* __restrict__ out, int N) {
    __shared__ alignas(16) unsigned short feat[32][136];
    __shared__ alignas(16) unsigned short h1s[32][136];

    const int tid  = threadIdx.x;
    const int wave = tid >> 6, lane = tid & 63;
    const int ro   = wave * 16;
    const int pbase = blockIdx.x * 32 + ro;

    {
        const int pt = lane >> 4, cg = lane & 15;
#pragma unroll
        for (int it = 0; it < 4; ++it) {
            int pl = it * 4 + pt;
            int p = min(pbase + pl, N - 1);
            PrepT a = prep(coords, p, cg);
            LdT   d = ld8(planeT, a);
            interp_store(&feat[ro + pl][cg * 8], a, d);
        }
    }
    __syncthreads();

    const int j = lane & 15, rg = lane >> 4;
    f32x4 acc[8];
#pragma unroll
    for (int nt = 0; nt < 8; ++nt) acc[nt] = (f32x4){0.f, 0.f, 0.f, 0.f};
#pragma unroll
    for (int kk = 0; kk < 4; ++kk) {
        bf16x8 a = __builtin_bit_cast(bf16x8, *reinterpret_cast<const uint4*>(&feat[ro + j][kk * 32 + rg * 8]));
#pragma unroll
        for (int nt = 0; nt < 8; ++nt) {
            bf16x8 b = __builtin_bit_cast(bf16x8, *reinterpret_cast<const uint4*>(W1b + (nt * 16 + j) * 128 + kk * 32 + rg * 8));
            acc[nt] = __builtin_amdgcn_mfma_f32_16x16x32_bf16(a, b, acc[nt], 0, 0, 0);
        }
    }
#pragma unroll
    for (int nt = 0; nt < 8; ++nt) {
        float bb = b1[nt * 16 + j];
#pragma unroll
        for (int r = 0; r < 4; ++r) {
            float h = __sinf(30.f * (acc[nt][r] + bb));
            h1s[ro + rg * 4 + r][nt * 16 + j] = f2bf(h);
        }
    }
    __syncthreads();

    f32x4 acc2[8];
#pragma unroll
    for (int nt = 0; nt < 8; ++nt) acc2[nt] = (f32x4){0.f, 0.f, 0.f, 0.f};
#pragma unroll
    for (int kk = 0; kk < 4; ++kk) {
        bf16x8 a = __builtin_bit_cast(bf16x8, *reinterpret_cast<const uint4*>(&h1s[ro + j][kk * 32 + rg * 8]));
#pragma unroll
        for (int nt = 0; nt < 8; ++nt) {
            bf16x8 b = __builtin_bit_cast(bf16x8, *reinterpret_cast<const uint4*>(W2b + (nt * 16 + j) * 128 + kk * 32 + rg * 8));
            acc2[nt] = __builtin_amdgcn_mfma_f32_16x16x32_bf16(a, b, acc2[nt], 0, 0, 0);
        }
    }

    float part[4] = {0.f, 0.f, 0.f, 0.f};
#pragma unroll
    for (int nt = 0; nt < 8; ++nt) {
        float bb = b2[nt * 16 + j];
        float w3 = W3[nt * 16 + j];
#pragma unroll
        for (int r = 0; r < 4; ++r)
            part[r] += __sinf(30.f * (acc2[nt][r] + bb)) * w3;
    }
#pragma unroll
    for (int off = 1; off < 16; off <<= 1) {
#pragma unroll
        for (int r = 0; r < 4; ++r) part[r] += __shfl_xor(part[r], off, 64);
    }
    if (j == 0) {
        float bb3 = b3[0];
#pragma unroll
        for (int r = 0; r < 4; ++r) {
            int p = pbase + rg * 4 + r;
            if (p < N) out[p] = part[r] + bb3;
        }
    }
}

extern "C" void kernel_launch(void* const* d_in, const int* in_sizes, int n_in,
                              void* d_out, int out_size, void* d_ws, size_t ws_size,
                              hipStream_t stream) {
    const float* coords = (const float*)d_in[0];
    const float* plane  = (const float*)d_in[1];
    const float* W1     = (const float*)d_in[4];
    const float* b1     = (const float*)d_in[5];
    const float* W2     = (const float*)d_in[6];
    const float* b2     = (const float*)d_in[7];
    const float* W3     = (const float*)d_in[8];
    const float* b3     = (const float*)d_in[9];
    float* out = (float*)d_out;
    int N = in_sizes[0] / 3;

    char* ws = (char*)d_ws;
    unsigned short* planeT = (unsigned short*)ws;                      // 16 MB
    unsigned short* W1b = (unsigned short*)(ws + 16777216);            // 32 KB
    unsigned short* W2b = (unsigned short*)(ws + 16809984);            // 32 KB

    k_transpose<<<dim3(HW * 8), dim3(256), 0, stream>>>(plane, planeT);
    k_wconv<<<dim3(128), dim3(256), 0, stream>>>(W1, W2, W1b, W2b);

    k_all<<<dim3(512), dim3(256), 0, stream>>>(coords, planeT, W1b, W2b,
                                               b1, b2, W3, b3, out, N);
    (void)ws_size;
}

// Round 9
// 129.601 us; speedup vs baseline: 4.0063x; 1.0556x over previous
//
#include <hip/hip_runtime.h>
#include <hip/hip_fp16.h>

typedef float f32x4 __attribute__((ext_vector_type(4)));
typedef _Float16 f16x8 __attribute__((ext_vector_type(8)));

#define CDIM 128
#define HW 256

// ---- kernel 1: transpose plane (C,H,W) f32 -> (H,W,C) f16 ----
__global__ __launch_bounds__(256) void k_transpose(const float* __restrict__ plane,
                                                   unsigned short* __restrict__ planeT) {
    __shared__ unsigned short tile[32][130];
    int tid = threadIdx.x;
    int y  = blockIdx.x >> 3;
    int x0 = (blockIdx.x & 7) * 32;
    int tx = tid & 31, tc = tid >> 5;
    for (int cc = 0; cc < 128; cc += 8) {
        int c = cc + tc;
        float v = plane[c * (HW * HW) + y * HW + x0 + tx];
        tile[tx][c] = __half_as_ushort(__float2half(v));
    }
    __syncthreads();
    for (int it = 0; it < 16; ++it) {
        int idx = it * 256 + tid;
        int c = idx & 127, xi = idx >> 7;
        planeT[(y * HW + x0 + xi) * CDIM + c] = tile[xi][c];
    }
}

// ---- kernel 2: convert W1,W2 f32 -> f16 ----
__global__ __launch_bounds__(256) void k_wconv(const float* __restrict__ W1,
                                               const float* __restrict__ W2,
                                               unsigned short* __restrict__ W1h,
                                               unsigned short* __restrict__ W2h) {
    int i = blockIdx.x * 256 + threadIdx.x;
    if (i < 16384) W1h[i] = __half_as_ushort(__float2half(W1[i]));
    else           W2h[i - 16384] = __half_as_ushort(__float2half(W2[i - 16384]));
}

// ---- gather helpers ((H,W,C) y-major layout) ----
// Weights held as broadcast half2: interp runs fully in packed f16
// (precision >= the old f32->bf16 path; features stored f16).
struct PrepT {
    int off[8];
    __half2 w[4];   // xy bilinear weights
    __half2 v[4];   // xz bilinear weights
};

__device__ __forceinline__ PrepT prep(const float* __restrict__ coords, int p, int cg) {
    PrepT r;
    float gx = coords[p * 3 + 0];
    float gy = coords[p * 3 + 1];
    float gz = coords[p * 3 + 2];
    float ix = (gx + 1.f) * 127.5f;
    float iy = (gy + 1.f) * 127.5f;
    float iz = (gz + 1.f) * 127.5f;
    float xf = floorf(ix), yf = floorf(iy), zf = floorf(iz);
    float wx1 = ix - xf, wy1 = iy - yf, wz1 = iz - zf;
    float wx0 = 1.f - wx1, wy0 = 1.f - wy1, wz0 = 1.f - wz1;
    int x0 = max(0, min((int)xf, HW - 1));
    int y0 = max(0, min((int)yf, HW - 1));
    int z0 = max(0, min((int)zf, HW - 1));
    int x1 = min(x0 + 1, HW - 1);
    int y1 = min(y0 + 1, HW - 1);
    int z1 = min(z0 + 1, HW - 1);
    int cx0 = x0 * CDIM + cg * 8, cx1 = x1 * CDIM + cg * 8;
    r.off[0] = (y0 << 15) + cx0; r.off[1] = (y0 << 15) + cx1;
    r.off[2] = (y1 << 15) + cx0; r.off[3] = (y1 << 15) + cx1;
    r.off[4] = (z0 << 15) + cx0; r.off[5] = (z0 << 15) + cx1;
    r.off[6] = (z1 << 15) + cx0; r.off[7] = (z1 << 15) + cx1;
    r.w[0] = __float2half2_rn(wy0 * wx0);
    r.w[1] = __float2half2_rn(wy0 * wx1);
    r.w[2] = __float2half2_rn(wy1 * wx0);
    r.w[3] = __float2half2_rn(wy1 * wx1);
    r.v[0] = __float2half2_rn(wz0 * wx0);
    r.v[1] = __float2half2_rn(wz0 * wx1);
    r.v[2] = __float2half2_rn(wz1 * wx0);
    r.v[3] = __float2half2_rn(wz1 * wx1);
    return r;
}

struct LdT { uint4 d[8]; };

__device__ __forceinline__ LdT ld8(const unsigned short* __restrict__ planeT, const PrepT& a) {
    LdT r;
#pragma unroll
    for (int c = 0; c < 8; ++c)
        r.d[c] = *reinterpret_cast<const uint4*>(planeT + a.off[c]);
    return r;
}

__device__ __forceinline__ __half2 geth2(const uint4& u, int g) {
    const unsigned* p = reinterpret_cast<const unsigned*>(&u);
    return __builtin_bit_cast(__half2, p[g]);
}

// packed-f16 interp: 10 pk ops per 2-channel group (was ~46 f32/cvt ops)
__device__ __forceinline__ void interp_store(unsigned short* dst, const PrepT& a, const LdT& L) {
    unsigned o[4];
#pragma unroll
    for (int g = 0; g < 4; ++g) {
        __half2 xy = __hmul2(a.w[0], geth2(L.d[0], g));
        xy = __hfma2(a.w[1], geth2(L.d[1], g), xy);
        xy = __hfma2(a.w[2], geth2(L.d[2], g), xy);
        xy = __hfma2(a.w[3], geth2(L.d[3], g), xy);
        __half2 xz = __hmul2(a.v[0], geth2(L.d[4], g));
        xz = __hfma2(a.v[1], geth2(L.d[5], g), xz);
        xz = __hfma2(a.v[2], geth2(L.d[6], g), xz);
        xz = __hfma2(a.v[3], geth2(L.d[7], g), xz);
        __half2 f = __hmul2(xy, __hmul2(xz, xz));
        o[g] = __builtin_bit_cast(unsigned, f);
    }
    uint4 pack; pack.x = o[0]; pack.y = o[1]; pack.z = o[2]; pack.w = o[3];
    *reinterpret_cast<uint4*>(dst) = pack;
}

// ---- kernel 3: fully fused gather + MLP (R8 structure, f16 numerics) ----
// 256 threads = 4 waves; W1+W2 staged once per block into LDS (swizzled);
// feat/h1 share a 16KB XOR-swizzled wave-private buffer. LDS = 80KB ->
// 2 blocks/CU. Grid-stride amortizes W staging. __syncthreads at every
// type-punned LDS producer->consumer edge (R2/R3 lesson).
__global__ __launch_bounds__(256, 2) void k_all(const float* __restrict__ coords,
                                                const unsigned short* __restrict__ planeT,
                                                const unsigned short* __restrict__ W1h,
                                                const unsigned short* __restrict__ W2h,
                                                const float* __restrict__ b1,
                                                const float* __restrict__ b2,
                                                const float* __restrict__ W3,
                                                const float* __restrict__ b3,
                                                float* __restrict__ out, int N) {
    __shared__ alignas(16) uint4 W1L[128][16];              // 32 KB, swizzled
    __shared__ alignas(16) uint4 W2L[128][16];              // 32 KB, swizzled
    __shared__ alignas(16) unsigned short featS[64][128];   // 16 KB, 16B-group swizzle

    const int tid  = threadIdx.x;
    const int wave = tid >> 6, lane = tid & 63;
    const int ro   = wave * 16;
    const int j = lane & 15, rg = lane >> 4;
    const int pt = lane >> 4, cg = lane & 15;   // gather roles

    // stage W into LDS (coalesced global read, swizzled LDS write)
#pragma unroll
    for (int i = 0; i < 8; ++i) {
        int idx = i * 256 + tid;
        int row = idx >> 4, col = idx & 15;
        W1L[row][col ^ (row & 15)] = reinterpret_cast<const uint4*>(W1h)[idx];
        W2L[row][col ^ (row & 15)] = reinterpret_cast<const uint4*>(W2h)[idx];
    }
    float b1v[8], b2v[8], w3v[8];
#pragma unroll
    for (int nt = 0; nt < 8; ++nt) {
        b1v[nt] = b1[nt * 16 + j];
        b2v[nt] = b2[nt * 16 + j];
        w3v[nt] = W3[nt * 16 + j];
    }
    const float bb3 = b3[0];
    __syncthreads();

    const int ntiles = (N + 63) >> 6;
    for (int t = blockIdx.x; t < ntiles; t += gridDim.x) {
        const int pbase = t * 64 + ro;

        // -------- phase A: gather 16 points/wave into swizzled featS --------
        {
            PrepT a0 = prep(coords, min(pbase + pt, N - 1), cg);
            LdT   d0 = ld8(planeT, a0);
#pragma unroll
            for (int it = 0; it < 3; ++it) {
                PrepT a1 = prep(coords, min(pbase + (it + 1) * 4 + pt, N - 1), cg);
                LdT   d1 = ld8(planeT, a1);
                int pl = it * 4 + pt;
                interp_store(&featS[ro + pl][(cg ^ pl) * 8], a0, d0);
                a0 = a1; d0 = d1;
            }
            int pl = 12 + pt;
            interp_store(&featS[ro + pl][(cg ^ pl) * 8], a0, d0);
        }

        __syncthreads();   // order feat ds_writes before GEMM1 ds_reads

        // -------- GEMM1: h1 = sin(30*(feat @ W1^T + b1)) --------
        f32x4 acc[8];
#pragma unroll
        for (int nt = 0; nt < 8; ++nt) acc[nt] = (f32x4){0.f, 0.f, 0.f, 0.f};

        f16x8 af[4];
#pragma unroll
        for (int kk = 0; kk < 4; ++kk)
            af[kk] = __builtin_bit_cast(f16x8, *reinterpret_cast<const uint4*>(&featS[ro + j][((kk * 4 + rg) ^ j) * 8]));

#pragma unroll
        for (int kk = 0; kk < 4; ++kk) {
            f16x8 bf[8];
#pragma unroll
            for (int nt = 0; nt < 8; ++nt)
                bf[nt] = __builtin_bit_cast(f16x8, W1L[nt * 16 + j][(kk * 4 + rg) ^ j]);
#pragma unroll
            for (int nt = 0; nt < 8; ++nt)
                acc[nt] = __builtin_amdgcn_mfma_f32_16x16x32_f16(af[kk], bf[nt], acc[nt], 0, 0, 0);
        }

        // h1 overwrites featS rows (wave-private; af already consumed by MFMA)
#pragma unroll
        for (int nt = 0; nt < 8; ++nt) {
#pragma unroll
            for (int r = 0; r < 4; ++r) {
                float h = __sinf(30.f * (acc[nt][r] + b1v[nt]));
                int row = rg * 4 + r;
                int g = (nt * 2 + (j >> 3)) ^ row;
                featS[ro + row][g * 8 + (j & 7)] = __half_as_ushort(__float2half(h));
            }
        }

        __syncthreads();   // order h1 ds_writes before GEMM2 ds_reads

        // -------- GEMM2: h2 = sin(30*(h1 @ W2^T + b2)) --------
        f32x4 acc2[8];
#pragma unroll
        for (int nt = 0; nt < 8; ++nt) acc2[nt] = (f32x4){0.f, 0.f, 0.f, 0.f};

        f16x8 af2[4];
#pragma unroll
        for (int kk = 0; kk < 4; ++kk)
            af2[kk] = __builtin_bit_cast(f16x8, *reinterpret_cast<const uint4*>(&featS[ro + j][((kk * 4 + rg) ^ j) * 8]));

#pragma unroll
        for (int kk = 0; kk < 4; ++kk) {
            f16x8 bf[8];
#pragma unroll
            for (int nt = 0; nt < 8; ++nt)
                bf[nt] = __builtin_bit_cast(f16x8, W2L[nt * 16 + j][(kk * 4 + rg) ^ j]);
#pragma unroll
            for (int nt = 0; nt < 8; ++nt)
                acc2[nt] = __builtin_amdgcn_mfma_f32_16x16x32_f16(af2[kk], bf[nt], acc2[nt], 0, 0, 0);
        }

        // -------- epilogue: out = h2 @ W3^T + b3 --------
        float part[4] = {0.f, 0.f, 0.f, 0.f};
#pragma unroll
        for (int nt = 0; nt < 8; ++nt) {
#pragma unroll
            for (int r = 0; r < 4; ++r)
                part[r] += __sinf(30.f * (acc2[nt][r] + b2v[nt])) * w3v[nt];
        }
#pragma unroll
        for (int off = 1; off < 16; off <<= 1) {
#pragma unroll
            for (int r = 0; r < 4; ++r) part[r] += __shfl_xor(part[r], off, 64);
        }
        if (j == 0) {
#pragma unroll
            for (int r = 0; r < 4; ++r) {
                int p = pbase + rg * 4 + r;
                if (p < N) out[p] = part[r] + bb3;
            }
        }

        __syncthreads();   // protect featS reads from next tile's gather writes
    }
}

extern "C" void kernel_launch(void* const* d_in, const int* in_sizes, int n_in,
                              void* d_out, int out_size, void* d_ws, size_t ws_size,
                              hipStream_t stream) {
    const float* coords = (const float*)d_in[0];
    const float* plane  = (const float*)d_in[1];
    const float* W1     = (const float*)d_in[4];
    const float* b1     = (const float*)d_in[5];
    const float* W2     = (const float*)d_in[6];
    const float* b2     = (const float*)d_in[7];
    const float* W3     = (const float*)d_in[8];
    const float* b3     = (const float*)d_in[9];
    float* out = (float*)d_out;
    int N = in_sizes[0] / 3;

    char* ws = (char*)d_ws;
    unsigned short* planeT = (unsigned short*)ws;                      // 16 MB
    unsigned short* W1h = (unsigned short*)(ws + 16777216);            // 32 KB
    unsigned short* W2h = (unsigned short*)(ws + 16809984);            // 32 KB

    k_transpose<<<dim3(HW * 8), dim3(256), 0, stream>>>(plane, planeT);
    k_wconv<<<dim3(128), dim3(256), 0, stream>>>(W1, W2, W1h, W2h);

    k_all<<<dim3(512), dim3(256), 0, stream>>>(coords, planeT, W1h, W2h,
                                               b1, b2, W3, b3, out, N);
    (void)ws_size;
}

// Round 10
// 125.935 us; speedup vs baseline: 4.1229x; 1.0291x over previous
//
#include <hip/hip_runtime.h>
#include <hip/hip_fp16.h>

typedef float f32x4 __attribute__((ext_vector_type(4)));
typedef _Float16 f16x8 __attribute__((ext_vector_type(8)));

#define CDIM 128
#define HW 256

// ---- kernel 1: transpose plane (C,H,W) f32 -> (H,W,C) f16 ----
__global__ __launch_bounds__(256) void k_transpose(const float* __restrict__ plane,
                                                   unsigned short* __restrict__ planeT) {
    __shared__ unsigned short tile[32][130];
    int tid = threadIdx.x;
    int y  = blockIdx.x >> 3;
    int x0 = (blockIdx.x & 7) * 32;
    int tx = tid & 31, tc = tid >> 5;
    for (int cc = 0; cc < 128; cc += 8) {
        int c = cc + tc;
        float v = plane[c * (HW * HW) + y * HW + x0 + tx];
        tile[tx][c] = __half_as_ushort(__float2half(v));
    }
    __syncthreads();
    for (int it = 0; it < 16; ++it) {
        int idx = it * 256 + tid;
        int c = idx & 127, xi = idx >> 7;
        planeT[(y * HW + x0 + xi) * CDIM + c] = tile[xi][c];
    }
}

// ---- kernel 2: convert W1,W2 f32 -> f16 ----
__global__ __launch_bounds__(256) void k_wconv(const float* __restrict__ W1,
                                               const float* __restrict__ W2,
                                               unsigned short* __restrict__ W1h,
                                               unsigned short* __restrict__ W2h) {
    int i = blockIdx.x * 256 + threadIdx.x;
    if (i < 16384) W1h[i] = __half_as_ushort(__float2half(W1[i]));
    else           W2h[i - 16384] = __half_as_ushort(__float2half(W2[i - 16384]));
}

// ---- gather helpers ((H,W,C) y-major layout) ----
struct PrepT {
    int off[8];
    __half2 w[4];   // xy bilinear weights
    __half2 v[4];   // xz bilinear weights
};

__device__ __forceinline__ PrepT prep(const float* __restrict__ coords, int p, int cg) {
    PrepT r;
    float gx = coords[p * 3 + 0];
    float gy = coords[p * 3 + 1];
    float gz = coords[p * 3 + 2];
    float ix = (gx + 1.f) * 127.5f;
    float iy = (gy + 1.f) * 127.5f;
    float iz = (gz + 1.f) * 127.5f;
    float xf = floorf(ix), yf = floorf(iy), zf = floorf(iz);
    float wx1 = ix - xf, wy1 = iy - yf, wz1 = iz - zf;
    float wx0 = 1.f - wx1, wy0 = 1.f - wy1, wz0 = 1.f - wz1;
    int x0 = max(0, min((int)xf, HW - 1));
    int y0 = max(0, min((int)yf, HW - 1));
    int z0 = max(0, min((int)zf, HW - 1));
    int x1 = min(x0 + 1, HW - 1);
    int y1 = min(y0 + 1, HW - 1);
    int z1 = min(z0 + 1, HW - 1);
    int cx0 = x0 * CDIM + cg * 8, cx1 = x1 * CDIM + cg * 8;
    r.off[0] = (y0 << 15) + cx0; r.off[1] = (y0 << 15) + cx1;
    r.off[2] = (y1 << 15) + cx0; r.off[3] = (y1 << 15) + cx1;
    r.off[4] = (z0 << 15) + cx0; r.off[5] = (z0 << 15) + cx1;
    r.off[6] = (z1 << 15) + cx0; r.off[7] = (z1 << 15) + cx1;
    r.w[0] = __float2half2_rn(wy0 * wx0);
    r.w[1] = __float2half2_rn(wy0 * wx1);
    r.w[2] = __float2half2_rn(wy1 * wx0);
    r.w[3] = __float2half2_rn(wy1 * wx1);
    r.v[0] = __float2half2_rn(wz0 * wx0);
    r.v[1] = __float2half2_rn(wz0 * wx1);
    r.v[2] = __float2half2_rn(wz1 * wx0);
    r.v[3] = __float2half2_rn(wz1 * wx1);
    return r;
}

struct LdT { uint4 d[8]; };

__device__ __forceinline__ LdT ld8(const unsigned short* __restrict__ planeT, const PrepT& a) {
    LdT r;
#pragma unroll
    for (int c = 0; c < 8; ++c)
        r.d[c] = *reinterpret_cast<const uint4*>(planeT + a.off[c]);
    return r;
}

__device__ __forceinline__ __half2 geth2(const uint4& u, int g) {
    const unsigned* p = reinterpret_cast<const unsigned*>(&u);
    return __builtin_bit_cast(__half2, p[g]);
}

// packed-f16 interp: 10 pk ops per 2-channel group
__device__ __forceinline__ void interp_store(unsigned short* dst, const PrepT& a, const LdT& L) {
    unsigned o[4];
#pragma unroll
    for (int g = 0; g < 4; ++g) {
        __half2 xy = __hmul2(a.w[0], geth2(L.d[0], g));
        xy = __hfma2(a.w[1], geth2(L.d[1], g), xy);
        xy = __hfma2(a.w[2], geth2(L.d[2], g), xy);
        xy = __hfma2(a.w[3], geth2(L.d[3], g), xy);
        __half2 xz = __hmul2(a.v[0], geth2(L.d[4], g));
        xz = __hfma2(a.v[1], geth2(L.d[5], g), xz);
        xz = __hfma2(a.v[2], geth2(L.d[6], g), xz);
        xz = __hfma2(a.v[3], geth2(L.d[7], g), xz);
        __half2 f = __hmul2(xy, __hmul2(xz, xz));
        o[g] = __builtin_bit_cast(unsigned, f);
    }
    uint4 pack; pack.x = o[0]; pack.y = o[1]; pack.z = o[2]; pack.w = o[3];
    *reinterpret_cast<uint4*>(dst) = pack;
}

// ---- kernel 3: fully fused gather + MLP (R9 structure, depth-4 gather) ----
// Single change vs R9: phase A issues ALL 4 preps + 32 corner loads before
// any interp (depth-2 -> depth-4; 256 -> 512 B/lane in flight). Occupancy is
// LDS-capped at 2 blocks/CU so the extra ~96 VGPR is free (budget 256).
// Discriminates H-lat (expect ~100us) vs H-bw fetch ceiling (expect null).
__global__ __launch_bounds__(256, 2) void k_all(const float* __restrict__ coords,
                                                const unsigned short* __restrict__ planeT,
                                                const unsigned short* __restrict__ W1h,
                                                const unsigned short* __restrict__ W2h,
                                                const float* __restrict__ b1,
                                                const float* __restrict__ b2,
                                                const float* __restrict__ W3,
                                                const float* __restrict__ b3,
                                                float* __restrict__ out, int N) {
    __shared__ alignas(16) uint4 W1L[128][16];              // 32 KB, swizzled
    __shared__ alignas(16) uint4 W2L[128][16];              // 32 KB, swizzled
    __shared__ alignas(16) unsigned short featS[64][128];   // 16 KB, 16B-group swizzle

    const int tid  = threadIdx.x;
    const int wave = tid >> 6, lane = tid & 63;
    const int ro   = wave * 16;
    const int j = lane & 15, rg = lane >> 4;
    const int pt = lane >> 4, cg = lane & 15;   // gather roles

    // stage W into LDS (coalesced global read, swizzled LDS write)
#pragma unroll
    for (int i = 0; i < 8; ++i) {
        int idx = i * 256 + tid;
        int row = idx >> 4, col = idx & 15;
        W1L[row][col ^ (row & 15)] = reinterpret_cast<const uint4*>(W1h)[idx];
        W2L[row][col ^ (row & 15)] = reinterpret_cast<const uint4*>(W2h)[idx];
    }
    float b1v[8], b2v[8], w3v[8];
#pragma unroll
    for (int nt = 0; nt < 8; ++nt) {
        b1v[nt] = b1[nt * 16 + j];
        b2v[nt] = b2[nt * 16 + j];
        w3v[nt] = W3[nt * 16 + j];
    }
    const float bb3 = b3[0];
    __syncthreads();

    const int ntiles = (N + 63) >> 6;
    for (int t = blockIdx.x; t < ntiles; t += gridDim.x) {
        const int pbase = t * 64 + ro;

        // -------- phase A: depth-4 gather, 16 points/wave into swizzled featS --------
        {
            PrepT a0 = prep(coords, min(pbase + 0 * 4 + pt, N - 1), cg);
            LdT   d0 = ld8(planeT, a0);
            PrepT a1 = prep(coords, min(pbase + 1 * 4 + pt, N - 1), cg);
            LdT   d1 = ld8(planeT, a1);
            PrepT a2 = prep(coords, min(pbase + 2 * 4 + pt, N - 1), cg);
            LdT   d2 = ld8(planeT, a2);
            PrepT a3 = prep(coords, min(pbase + 3 * 4 + pt, N - 1), cg);
            LdT   d3 = ld8(planeT, a3);
            interp_store(&featS[ro + 0 * 4 + pt][(cg ^ (0 * 4 + pt)) * 8], a0, d0);
            interp_store(&featS[ro + 1 * 4 + pt][(cg ^ (1 * 4 + pt)) * 8], a1, d1);
            interp_store(&featS[ro + 2 * 4 + pt][(cg ^ (2 * 4 + pt)) * 8], a2, d2);
            interp_store(&featS[ro + 3 * 4 + pt][(cg ^ (3 * 4 + pt)) * 8], a3, d3);
        }

        __syncthreads();   // order feat ds_writes before GEMM1 ds_reads

        // -------- GEMM1: h1 = sin(30*(feat @ W1^T + b1)) --------
        f32x4 acc[8];
#pragma unroll
        for (int nt = 0; nt < 8; ++nt) acc[nt] = (f32x4){0.f, 0.f, 0.f, 0.f};

        f16x8 af[4];
#pragma unroll
        for (int kk = 0; kk < 4; ++kk)
            af[kk] = __builtin_bit_cast(f16x8, *reinterpret_cast<const uint4*>(&featS[ro + j][((kk * 4 + rg) ^ j) * 8]));

#pragma unroll
        for (int kk = 0; kk < 4; ++kk) {
            f16x8 bf[8];
#pragma unroll
            for (int nt = 0; nt < 8; ++nt)
                bf[nt] = __builtin_bit_cast(f16x8, W1L[nt * 16 + j][(kk * 4 + rg) ^ j]);
#pragma unroll
            for (int nt = 0; nt < 8; ++nt)
                acc[nt] = __builtin_amdgcn_mfma_f32_16x16x32_f16(af[kk], bf[nt], acc[nt], 0, 0, 0);
        }

        // h1 overwrites featS rows (wave-private; af already consumed by MFMA)
#pragma unroll
        for (int nt = 0; nt < 8; ++nt) {
#pragma unroll
            for (int r = 0; r < 4; ++r) {
                float h = __sinf(30.f * (acc[nt][r] + b1v[nt]));
                int row = rg * 4 + r;
                int g = (nt * 2 + (j >> 3)) ^ row;
                featS[ro + row][g * 8 + (j & 7)] = __half_as_ushort(__float2half(h));
            }
        }

        __syncthreads();   // order h1 ds_writes before GEMM2 ds_reads

        // -------- GEMM2: h2 = sin(30*(h1 @ W2^T + b2)) --------
        f32x4 acc2[8];
#pragma unroll
        for (int nt = 0; nt < 8; ++nt) acc2[nt] = (f32x4){0.f, 0.f, 0.f, 0.f};

        f16x8 af2[4];
#pragma unroll
        for (int kk = 0; kk < 4; ++kk)
            af2[kk] = __builtin_bit_cast(f16x8, *reinterpret_cast<const uint4*>(&featS[ro + j][((kk * 4 + rg) ^ j) * 8]));

#pragma unroll
        for (int kk = 0; kk < 4; ++kk) {
            f16x8 bf[8];
#pragma unroll
            for (int nt = 0; nt < 8; ++nt)
                bf[nt] = __builtin_bit_cast(f16x8, W2L[nt * 16 + j][(kk * 4 + rg) ^ j]);
#pragma unroll
            for (int nt = 0; nt < 8; ++nt)
                acc2[nt] = __builtin_amdgcn_mfma_f32_16x16x32_f16(af2[kk], bf[nt], acc2[nt], 0, 0, 0);
        }

        // -------- epilogue: out = h2 @ W3^T + b3 --------
        float part[4] = {0.f, 0.f, 0.f, 0.f};
#pragma unroll
        for (int nt = 0; nt < 8; ++nt) {
#pragma unroll
            for (int r = 0; r < 4; ++r)
                part[r] += __sinf(30.f * (acc2[nt][r] + b2v[nt])) * w3v[nt];
        }
#pragma unroll
        for (int off = 1; off < 16; off <<= 1) {
#pragma unroll
            for (int r = 0; r < 4; ++r) part[r] += __shfl_xor(part[r], off, 64);
        }
        if (j == 0) {
#pragma unroll
            for (int r = 0; r < 4; ++r) {
                int p = pbase + rg * 4 + r;
                if (p < N) out[p] = part[r] + bb3;
            }
        }

        __syncthreads();   // protect featS reads from next tile's gather writes
    }
}

extern "C" void kernel_launch(void* const* d_in, const int* in_sizes, int n_in,
                              void* d_out, int out_size, void* d_ws, size_t ws_size,
                              hipStream_t stream) {
    const float* coords = (const float*)d_in[0];
    const float* plane  = (const float*)d_in[1];
    const float* W1     = (const float*)d_in[4];
    const float* b1     = (const float*)d_in[5];
    const float* W2     = (const float*)d_in[6];
    const float* b2     = (const float*)d_in[7];
    const float* W3     = (const float*)d_in[8];
    const float* b3     = (const float*)d_in[9];
    float* out = (float*)d_out;
    int N = in_sizes[0] / 3;

    char* ws = (char*)d_ws;
    unsigned short* planeT = (unsigned short*)ws;                      // 16 MB
    unsigned short* W1h = (unsigned short*)(ws + 16777216);            // 32 KB
    unsigned short* W2h = (unsigned short*)(ws + 16809984);            // 32 KB

    k_transpose<<<dim3(HW * 8), dim3(256), 0, stream>>>(plane, planeT);
    k_wconv<<<dim3(128), dim3(256), 0, stream>>>(W1, W2, W1h, W2h);

    k_all<<<dim3(512), dim3(256), 0, stream>>>(coords, planeT, W1h, W2h,
                                               b1, b2, W3, b3, out, N);
    (void)ws_size;
}